// Round 1
// baseline (914.561 us; speedup 1.0000x reference)
//
#include <hip/hip_runtime.h>
#include <hip/hip_bf16.h>

#define TT 2048
#define BB 16
#define DD 1024
#define BD (BB*DD)          // 16384 cols per time row
#define MR (TT*BB)          // 32768 GEMM rows
#define EPSV 1e-6f
#define CH 256              // phase-B chunk length
#define NCH (TT/CH)         // 8

typedef __bf16 bf16x8_t __attribute__((ext_vector_type(8)));
typedef float  f32x4_t  __attribute__((ext_vector_type(4)));
typedef __attribute__((address_space(1))) void gvoid_t;
typedef __attribute__((address_space(3))) void lvoid_t;

static __device__ __forceinline__ unsigned short f2bf(float f) {
    __hip_bfloat16 h = __float2bfloat16(f);
    return __builtin_bit_cast(unsigned short, h);
}

// ---------------------------------------------------------------------------
// K0: convert x and W to bf16 (stored in the h-region of d_out, dead space
// until phase A/B overwrite it after the GEMM has consumed it).
// ---------------------------------------------------------------------------
__global__ void k_convert(const float* __restrict__ x, const float* __restrict__ W,
                          unsigned short* __restrict__ xb, unsigned short* __restrict__ wb) {
    const long NX4 = (long)MR * DD / 4;
    const long NW4 = (long)DD * DD / 4;
    const long stride = (long)gridDim.x * blockDim.x;
    for (long j = (long)blockIdx.x * blockDim.x + threadIdx.x; j < NX4 + NW4; j += stride) {
        const float4* src; unsigned short* dst; long o;
        if (j < NX4) { src = (const float4*)x; dst = xb; o = j; }
        else         { src = (const float4*)W; dst = wb; o = j - NX4; }
        float4 v = src[o];
        ushort4 u;
        u.x = f2bf(v.x); u.y = f2bf(v.y); u.z = f2bf(v.z); u.w = f2bf(v.w);
        *(ushort4*)(dst + o * 4) = u;
    }
}

// ---------------------------------------------------------------------------
// K1: Wx = x @ W^T + b  (bf16 MFMA, f32 accumulate/output).
// A [MR][DD] row-major bf16, Bw = W [DD][DD] row-major bf16 (B^T-form GEMM).
// 128x128 tile, BK=32, 4 waves in 2x2, each wave 4x4 of 16x16x32 MFMA.
// ---------------------------------------------------------------------------
__global__ __launch_bounds__(256, 2)
void k_gemm(const unsigned short* __restrict__ A, const unsigned short* __restrict__ Bw,
            const float* __restrict__ bias, float* __restrict__ C) {
    __shared__ char lds[16384];
    char* ldsA = lds;
    char* ldsB = lds + 8192;
    const int tid  = threadIdx.x;
    const int lane = tid & 63;
    const int wid  = tid >> 6;
    const int wm = wid >> 1, wn = wid & 1;
    const size_t arow0 = (size_t)blockIdx.y * 128;
    const int    brow0 = blockIdx.x * 128;

    f32x4_t acc[4][4] = {};

    // staging: 256 threads x 16B x 2 rounds = 8KB tile ([row][k] rows of 64B)
    const int off0 = tid * 16,        row0_ = off0 >> 6, colb0 = off0 & 63;
    const int off1 = 4096 + tid * 16, row1_ = off1 >> 6, colb1 = off1 & 63;

    for (int kk = 0; kk < DD / 32; ++kk) {
        const int kbase = kk * 32;
        __builtin_amdgcn_global_load_lds(
            (gvoid_t*)(A + (arow0 + row0_) * DD + kbase + (colb0 >> 1)),
            (lvoid_t*)(ldsA + off0), 16, 0, 0);
        __builtin_amdgcn_global_load_lds(
            (gvoid_t*)(A + (arow0 + row1_) * DD + kbase + (colb1 >> 1)),
            (lvoid_t*)(ldsA + off1), 16, 0, 0);
        __builtin_amdgcn_global_load_lds(
            (gvoid_t*)(Bw + (size_t)(brow0 + row0_) * DD + kbase + (colb0 >> 1)),
            (lvoid_t*)(ldsB + off0), 16, 0, 0);
        __builtin_amdgcn_global_load_lds(
            (gvoid_t*)(Bw + (size_t)(brow0 + row1_) * DD + kbase + (colb1 >> 1)),
            (lvoid_t*)(ldsB + off1), 16, 0, 0);
        __syncthreads();

        const int ml = lane & 15;
        const int kh = (lane >> 4) * 16;   // byte offset of this lane's k-slice
        bf16x8_t av[4], bv[4];
        #pragma unroll
        for (int i = 0; i < 4; ++i) {
            av[i] = *(const bf16x8_t*)(ldsA + (wm * 64 + i * 16 + ml) * 64 + kh);
            bv[i] = *(const bf16x8_t*)(ldsB + (wn * 64 + i * 16 + ml) * 64 + kh);
        }
        #pragma unroll
        for (int i = 0; i < 4; ++i)
            #pragma unroll
            for (int j = 0; j < 4; ++j)
                acc[i][j] = __builtin_amdgcn_mfma_f32_16x16x32_bf16(av[i], bv[j], acc[i][j], 0, 0, 0);
        __syncthreads();
    }

    // C/D layout: col = lane&15, row = (lane>>4)*4 + reg   [verified mapping]
    const int rq = (lane >> 4) * 4;
    const int cl = lane & 15;
    #pragma unroll
    for (int i = 0; i < 4; ++i) {
        #pragma unroll
        for (int j = 0; j < 4; ++j) {
            const int n = brow0 + wn * 64 + j * 16 + cl;
            const float bb = bias[n];
            #pragma unroll
            for (int q = 0; q < 4; ++q) {
                const size_t m = arow0 + wm * 64 + i * 16 + rq + q;
                C[m * DD + n] = acc[i][j][q] + bb;
            }
        }
    }
}

// ---------------------------------------------------------------------------
// K2: phase A — sequential scan, one wave per batch row, h in registers.
// Emits r_t scalars and h snapshots every CH steps (written at their FINAL
// h-output positions). Depth-8 register prefetch ring on the Wx rows.
// ---------------------------------------------------------------------------
__global__ __launch_bounds__(64, 1)
void k_phaseA(const float* __restrict__ Wx, const float* __restrict__ h0,
              const float* __restrict__ la, float* __restrict__ hout,
              float* __restrict__ rtab) {
    const int b = blockIdx.x;
    const int lane = threadIdx.x;
    const float alpha = expf(la[0]);
    const int dof = lane * 4;   // this lane's offset within each 256-float group

    float h[16];
    #pragma unroll
    for (int k = 0; k < 4; ++k) {
        float4 v = *(const float4*)(h0 + b * DD + k * 256 + dof);
        h[k*4+0] = v.x; h[k*4+1] = v.y; h[k*4+2] = v.z; h[k*4+3] = v.w;
    }

    float4 buf[8][4];                       // prefetch ring, all indices static
    #pragma unroll
    for (int s = 0; s < 8; ++s) {
        const float* wp = Wx + (size_t)s * BD + b * DD;   // row for t = s+1
        #pragma unroll
        for (int k = 0; k < 4; ++k) buf[s][k] = *(const float4*)(wp + k * 256 + dof);
    }

    float* rrow = rtab + b * TT;

    for (int tt = 1; tt <= TT; tt += 8) {
        #pragma unroll
        for (int s = 0; s < 8; ++s) {
            const int t = tt + s;
            if (((t - 1) & (CH - 1)) == 0) {            // snapshot h_{t-1}
                float* hp = hout + (size_t)(t - 1) * BD + b * DD;
                #pragma unroll
                for (int k = 0; k < 4; ++k) {
                    float4 v; v.x = h[k*4+0]; v.y = h[k*4+1]; v.z = h[k*4+2]; v.w = h[k*4+3];
                    *(float4*)(hp + k * 256 + dof) = v;
                }
            }
            float hr[16];
            float s0 = 0.f, s1 = 0.f, s2 = 0.f, s3 = 0.f;
            #pragma unroll
            for (int k = 0; k < 4; ++k) {
                float4 w = buf[s][k];
                hr[k*4+0] = fmaf(alpha, w.x, h[k*4+0]);
                hr[k*4+1] = fmaf(alpha, w.y, h[k*4+1]);
                hr[k*4+2] = fmaf(alpha, w.z, h[k*4+2]);
                hr[k*4+3] = fmaf(alpha, w.w, h[k*4+3]);
                s0 = fmaf(hr[k*4+0], hr[k*4+0], s0);
                s1 = fmaf(hr[k*4+1], hr[k*4+1], s1);
                s2 = fmaf(hr[k*4+2], hr[k*4+2], s2);
                s3 = fmaf(hr[k*4+3], hr[k*4+3], s3);
            }
            float ss = (s0 + s1) + (s2 + s3);
            #pragma unroll
            for (int m = 1; m < 64; m <<= 1) ss += __shfl_xor(ss, m, 64);
            const float r = rsqrtf(ss * (1.0f / DD) + EPSV);
            if (lane == 0) rrow[t - 1] = r;
            #pragma unroll
            for (int e = 0; e < 16; ++e) h[e] = r * hr[e];
            if (t + 8 <= TT) {                           // refill slot s with row t+7 (for t+8)
                const float* wp = Wx + (size_t)(t + 7) * BD + b * DD;
                #pragma unroll
                for (int k = 0; k < 4; ++k) buf[s][k] = *(const float4*)(wp + k * 256 + dof);
            }
        }
    }
}

// ---------------------------------------------------------------------------
// K3: phase B — parallel replay. Grid (col-block, chunk). Each thread owns one
// column, walks its chunk using the r-table, reads Wx and overwrites it in
// place with `out` (read-then-write by the same thread), writes h rows.
// ---------------------------------------------------------------------------
__global__ __launch_bounds__(256)
void k_phaseB(float* __restrict__ WxOut, float* __restrict__ hout,
              const float* __restrict__ rtab, const float* __restrict__ la) {
    const int col = blockIdx.x * 256 + threadIdx.x;
    const int c = blockIdx.y;
    const int b = col >> 10;                 // uniform per block (256 | 1024)
    const float alpha = expf(la[0]);
    const float* rr = rtab + b * TT;
    float h = hout[(size_t)(c * CH) * BD + col];   // phase-A snapshot
    const int t0 = c * CH + 1;
    float w = WxOut[(size_t)(t0 - 1) * BD + col];
    for (int s = 0; s < CH; ++s) {
        const int t = t0 + s;
        float wnext = 0.f;
        if (s + 1 < CH) wnext = WxOut[(size_t)t * BD + col];
        const float r = rr[t - 1];
        const float hraw = fmaf(alpha, w, h);
        const float hn = r * hraw;
        const float sg = 1.0f / (1.0f + __expf(-hn));
        WxOut[(size_t)(t - 1) * BD + col] = hn * hn * sg;   // out_t = hn * silu(hn)
        if ((t & (CH - 1)) != 0 || t == TT)                  // snapshot rows owned by phase A
            hout[(size_t)t * BD + col] = hn;
        h = hn;
        w = wnext;
    }
}

// ---------------------------------------------------------------------------
extern "C" void kernel_launch(void* const* d_in, const int* in_sizes, int n_in,
                              void* d_out, int out_size, void* d_ws, size_t ws_size,
                              hipStream_t stream) {
    (void)in_sizes; (void)n_in; (void)out_size; (void)ws_size;
    const float* x    = (const float*)d_in[0];
    const float* h0   = (const float*)d_in[1];
    const float* W    = (const float*)d_in[2];
    const float* bias = (const float*)d_in[3];
    const float* la   = (const float*)d_in[4];

    float* outr = (float*)d_out;                       // [T][B*D] : Wx, then out
    float* hreg = outr + (size_t)TT * BD;              // [T+1][B*D] : h output
    unsigned short* xb = (unsigned short*)hreg;        // bf16 x (67MB, dead space pre-phase-A)
    unsigned short* wb = xb + (size_t)MR * DD;         // bf16 W (2MB)
    float* rtab = (float*)d_ws;                        // [B][T] = 128KB

    k_convert<<<2048, 256, 0, stream>>>(x, W, xb, wb);
    k_gemm<<<dim3(DD / 128, MR / 128), 256, 0, stream>>>(xb, wb, bias, outr);
    k_phaseA<<<BB, 64, 0, stream>>>(outr, h0, la, hreg, rtab);
    k_phaseB<<<dim3(BD / 256, NCH), 256, 0, stream>>>(outr, hreg, rtab, la);
}